// Round 6
// baseline (91.178 us; speedup 1.0000x reference)
//
#include <hip/hip_runtime.h>
#include <hip/hip_bf16.h>

#define NROWS 8192
#define DIM 128

typedef short short8 __attribute__((ext_vector_type(8)));
typedef float f32x4 __attribute__((ext_vector_type(4)));
typedef unsigned short ushort4v __attribute__((ext_vector_type(4)));

__device__ __forceinline__ unsigned short bf16r(float f) {
  unsigned int u = __builtin_bit_cast(unsigned int, f);
  u += 0x7fffu + ((u >> 16) & 1u);   // round-to-nearest-even
  return (unsigned short)(u >> 16);
}
__device__ __forceinline__ short8 asbf8(uint4 v) { return __builtin_bit_cast(short8, v); }

__device__ __forceinline__ unsigned cvtpk_bf16(float lo, float hi) {
  unsigned r;
  asm("v_cvt_pk_bf16_f32 %0, %1, %2" : "=v"(r) : "v"(lo), "v"(hi));
  return r;
}

// async global->LDS, 16B per lane; LDS dest must be linear (base + lane*16)
__device__ __forceinline__ void gload_lds16(const void* g, void* l) {
  __builtin_amdgcn_global_load_lds(
      (const __attribute__((address_space(1))) void*)g,
      (__attribute__((address_space(3))) void*)l, 16, 0, 0);
}

// ------------------------- QKV projection (f32, LDS-staged) -------------------------
// Q is pre-scaled by log2(e) so attention can use exp2 directly.
__global__ __launch_bounds__(256) void qkv_proj(
    const float* __restrict__ x, const float* __restrict__ W, const float* __restrict__ bias,
    unsigned short* __restrict__ Q, unsigned short* __restrict__ K, unsigned short* __restrict__ Vt)
{
  __shared__ float sX[64 * 132];
  __shared__ float sW[64 * 132];
  __shared__ unsigned short sT[64 * 72];

  const int rt = blockIdx.x;                // 128 row tiles of 64
  const int ct = blockIdx.y;                // 6 col tiles of 64 (0,1->Q 2,3->K 4,5->V)
  const int t = threadIdx.x;

  const float4* xg = (const float4*)(x + (size_t)rt * 64 * DIM);
  const float4* wg = (const float4*)(W + (size_t)ct * 64 * DIM);
#pragma unroll
  for (int j = 0; j < 8; j++) {
    int i = t + 256 * j;
    int row = i >> 5, c4 = i & 31;
    *(float4*)&sX[row * 132 + c4 * 4] = xg[i];
    *(float4*)&sW[row * 132 + c4 * 4] = wg[i];
  }
  __syncthreads();

  const int tx = t & 15, ty = t >> 4;
  const int c0 = ct * 64 + tx * 4;

  float acc[4][4] = {};
#pragma unroll 8
  for (int k4 = 0; k4 < 32; k4++) {
    float4 xv[4], wv[4];
#pragma unroll
    for (int i = 0; i < 4; i++) xv[i] = *(const float4*)&sX[(ty * 4 + i) * 132 + k4 * 4];
#pragma unroll
    for (int j = 0; j < 4; j++) wv[j] = *(const float4*)&sW[(tx * 4 + j) * 132 + k4 * 4];
#pragma unroll
    for (int i = 0; i < 4; i++)
#pragma unroll
      for (int j = 0; j < 4; j++) {
        float s = acc[i][j];
        s = fmaf(xv[i].x, wv[j].x, s);
        s = fmaf(xv[i].y, wv[j].y, s);
        s = fmaf(xv[i].z, wv[j].z, s);
        s = fmaf(xv[i].w, wv[j].w, s);
        acc[i][j] = s;
      }
  }

  float bv[4];
#pragma unroll
  for (int j = 0; j < 4; j++) bv[j] = bias[c0 + j];

  if (ct < 4) {
    unsigned short* dst = (ct < 2) ? Q : K;
    const int cc = (ct < 2) ? c0 : c0 - 128;
    const float scale = (ct < 2) ? 1.44269504088896f : 1.0f;   // log2(e) folded into Q
#pragma unroll
    for (int i = 0; i < 4; i++) {
      int row = rt * 64 + ty * 4 + i;
      ushort4v h;
#pragma unroll
      for (int j = 0; j < 4; j++) h[j] = bf16r((acc[i][j] + bv[j]) * scale);
      *(ushort4v*)&dst[(size_t)row * DIM + cc] = h;
    }
  } else {
#pragma unroll
    for (int i = 0; i < 4; i++)
#pragma unroll
      for (int j = 0; j < 4; j++)
        sT[(tx * 4 + j) * 72 + ty * 4 + i] = bf16r(acc[i][j] + bv[j]);
    __syncthreads();
    const int dl = t & 63, chunk = t >> 6;
    const int dg = (ct - 4) * 64 + dl;
    uint4* dst = (uint4*)(Vt + (size_t)dg * NROWS + rt * 64 + chunk * 16);
    const uint4* src = (const uint4*)&sT[dl * 72 + chunk * 16];
    dst[0] = src[0];
    dst[1] = src[1];
  }
}

// ------------------------- flash attention (bf16 MFMA, swapped operands) -------------------------
// S^T = mfma(A=K, B=Q): lane (r,g) reg holds S[q=u*16+r][k=16kc+4g+reg].
// p = exp2(s) (Q pre-scaled); P^T packed to bf16 in-register (cvt_pk) and moved to
// the PV B-fragment layout with ds_bpermute (no LDS P buffer).
// O^T = mfma(A=V^T, B=P^T). K single-buffered, V double-buffered (48 KB LDS,
// 3 blocks/CU); staging via global_load_lds with pre-swizzled source addresses.
__global__ __launch_bounds__(256, 3) void attn(
    const unsigned short* __restrict__ Q, const unsigned short* __restrict__ K,
    const unsigned short* __restrict__ Vt,
    unsigned short* __restrict__ Opb, float* __restrict__ Lp,
    float* __restrict__ outDirect, int kvlen)
{
  __shared__ uint4 sK[64 * 16];                // K tile [64][128] bf16, swizzled
  __shared__ uint4 sV[2][128 * 8];             // Vt tile [128][64] bf16, swizzled, dbuf

  const int t = threadIdx.x;
  const int w = t >> 6, l = t & 63;
  const int r = l & 15, g = l >> 4;
  const int qt = blockIdx.x, sp = blockIdx.y;
  const int qbase = qt * 128 + w * 32;         // 32 q-rows per wave
  const int kb0 = sp * kvlen;
  const int rx = r & 7;
  const bool upper = (l >= 32);
  const int srcA4 = (r + 32 * (g & 1)) * 4;    // bpermute byte index, m=0,1 slots
  const int srcB4 = srcA4 + 64;                // +16 lanes, m=2,3 slots

  // ---- staging geometry: slot p = j*256 + t (linear LDS dest) ----
  const unsigned short* kgp[4];
  const unsigned short* vgp[4];
#pragma unroll
  for (int j = 0; j < 4; j++) {
    int p = t + 256 * j;
    int krow = p >> 4, kc16 = (p & 15) ^ (krow & 7);
    kgp[j] = K + (size_t)(kb0 + krow) * DIM + kc16 * 8;
    int vrow = p >> 3, vd16 = (p & 7) ^ (vrow & 7);
    vgp[j] = Vt + (size_t)vrow * NROWS + kb0 + vd16 * 8;
  }

  uint4 qf[2][4];
#pragma unroll
  for (int u = 0; u < 2; u++) {
    const uint4* Qv = (const uint4*)(Q + (size_t)(qbase + u * 16 + r) * DIM);
#pragma unroll
    for (int f = 0; f < 4; f++) qf[u][f] = Qv[f * 4 + g];
  }

  float lsum[2] = {0.f, 0.f};
  f32x4 oacc[2][8];
#pragma unroll
  for (int u = 0; u < 2; u++)
#pragma unroll
    for (int dc = 0; dc < 8; dc++) oacc[u][dc] = (f32x4){0.f, 0.f, 0.f, 0.f};

  const int niter = kvlen >> 6;

  // prologue: stage tile 0
#pragma unroll
  for (int j = 0; j < 4; j++) {
    gload_lds16(kgp[j], (uint4*)sK + (t + 256 * j));
    gload_lds16(vgp[j], (uint4*)sV[0] + (t + 256 * j));
  }
  __syncthreads();

  int cur = 0;
  for (int it = 0; it < niter; ++it) {
    // ---- prefetch V(it+1) into the other V buffer (lands during QK) ----
    if (it + 1 < niter) {
      const size_t voff = (size_t)(it + 1) * 64;
#pragma unroll
      for (int j = 0; j < 4; j++)
        gload_lds16(vgp[j] + voff, (uint4*)sV[cur ^ 1] + (t + 256 * j));
    }

    // ---- S^T = K Q^T (swapped operands; same LDS loads) ----
    f32x4 sacc[2][4];
#pragma unroll
    for (int u = 0; u < 2; u++)
#pragma unroll
      for (int kc = 0; kc < 4; kc++) sacc[u][kc] = (f32x4){0.f, 0.f, 0.f, 0.f};
#pragma unroll
    for (int kc = 0; kc < 4; kc++)
#pragma unroll
      for (int f = 0; f < 4; f++) {
        uint4 kf = sK[(kc * 16 + r) * 16 + ((f * 4 + g) ^ rx)];
        sacc[0][kc] = __builtin_amdgcn_mfma_f32_16x16x32_bf16(asbf8(kf), asbf8(qf[0][f]), sacc[0][kc], 0, 0, 0);
        sacc[1][kc] = __builtin_amdgcn_mfma_f32_16x16x32_bf16(asbf8(kf), asbf8(qf[1][f]), sacc[1][kc], 0, 0, 0);
      }

    __syncthreads();                           // barrier A: sK readers done; V(it+1) drained
    if (it + 1 < niter) {                      // K(it+1) lands during softmax+PV
      const size_t koff = (size_t)(it + 1) * 64 * DIM;
#pragma unroll
      for (int j = 0; j < 4; j++)
        gload_lds16(kgp[j] + koff, (uint4*)sK + (t + 256 * j));
    }

    // ---- p = exp2(s); per-lane partial sums; pack pairs to bf16 ----
    unsigned c32[2][4][2];
#pragma unroll
    for (int u = 0; u < 2; u++)
#pragma unroll
      for (int kc = 0; kc < 4; kc++) {
        float p0 = __builtin_amdgcn_exp2f(sacc[u][kc][0]);
        float p1 = __builtin_amdgcn_exp2f(sacc[u][kc][1]);
        float p2 = __builtin_amdgcn_exp2f(sacc[u][kc][2]);
        float p3 = __builtin_amdgcn_exp2f(sacc[u][kc][3]);
        lsum[u] += (p0 + p1) + (p2 + p3);
        c32[u][kc][0] = cvtpk_bf16(p0, p1);
        c32[u][kc][1] = cvtpk_bf16(p2, p3);
      }

    // ---- redistribute P^T to B-fragment layout (in-register, ds_bpermute) ----
    // dst lane (r,g) ka, elem jj: src lane r+16*(2*(g&1)+(jj>>2)), kc=2ka+(g>=2), reg=jj&3
    uint4 bfrag[2][2];
#pragma unroll
    for (int u = 0; u < 2; u++)
#pragma unroll
      for (int ka = 0; ka < 2; ka++) {
        int cA0 = (int)c32[u][2 * ka][0],     cA1 = (int)c32[u][2 * ka][1];
        int cB0 = (int)c32[u][2 * ka + 1][0], cB1 = (int)c32[u][2 * ka + 1][1];
        unsigned a0 = (unsigned)__builtin_amdgcn_ds_bpermute(srcA4, cA0);
        unsigned b0 = (unsigned)__builtin_amdgcn_ds_bpermute(srcA4, cB0);
        unsigned a1 = (unsigned)__builtin_amdgcn_ds_bpermute(srcA4, cA1);
        unsigned b1 = (unsigned)__builtin_amdgcn_ds_bpermute(srcA4, cB1);
        unsigned a2 = (unsigned)__builtin_amdgcn_ds_bpermute(srcB4, cA0);
        unsigned b2 = (unsigned)__builtin_amdgcn_ds_bpermute(srcB4, cB0);
        unsigned a3 = (unsigned)__builtin_amdgcn_ds_bpermute(srcB4, cA1);
        unsigned b3 = (unsigned)__builtin_amdgcn_ds_bpermute(srcB4, cB1);
        uint4 bf;
        bf.x = upper ? b0 : a0;
        bf.y = upper ? b1 : a1;
        bf.z = upper ? b2 : a2;
        bf.w = upper ? b3 : a3;
        bfrag[u][ka] = bf;
      }

    // ---- O^T += V^T P^T (vf shared across both q-subtiles) ----
#pragma unroll
    for (int dc = 0; dc < 8; dc++) {
      uint4 vf0 = sV[cur][(dc * 16 + r) * 8 + (g ^ rx)];
      uint4 vf1 = sV[cur][(dc * 16 + r) * 8 + ((4 + g) ^ rx)];
      oacc[0][dc] = __builtin_amdgcn_mfma_f32_16x16x32_bf16(asbf8(vf0), asbf8(bfrag[0][0]), oacc[0][dc], 0, 0, 0);
      oacc[0][dc] = __builtin_amdgcn_mfma_f32_16x16x32_bf16(asbf8(vf1), asbf8(bfrag[0][1]), oacc[0][dc], 0, 0, 0);
      oacc[1][dc] = __builtin_amdgcn_mfma_f32_16x16x32_bf16(asbf8(vf0), asbf8(bfrag[1][0]), oacc[1][dc], 0, 0, 0);
      oacc[1][dc] = __builtin_amdgcn_mfma_f32_16x16x32_bf16(asbf8(vf1), asbf8(bfrag[1][1]), oacc[1][dc], 0, 0, 0);
    }

    __syncthreads();                           // barrier B: sV[cur] free; K(it+1) drained
    cur ^= 1;
  }

  // ---- reduce row-sums across the 4 g-groups ----
#pragma unroll
  for (int u = 0; u < 2; u++) {
    float v = lsum[u];
    v += __shfl_xor(v, 16);
    v += __shfl_xor(v, 32);
    lsum[u] = v;
  }

  // ---- epilogue: lane (r,g) holds O^T[d=16dc+4g+reg][q=qbase+u*16+r] ----
  if (outDirect) {
#pragma unroll
    for (int u = 0; u < 2; u++) {
      float inv = 1.f / lsum[u];
      int q = qbase + u * 16 + r;
#pragma unroll
      for (int dc = 0; dc < 8; dc++) {
        f32x4 o = oacc[u][dc] * inv;
        *(f32x4*)&outDirect[(size_t)q * DIM + dc * 16 + 4 * g] = o;
      }
    }
  } else {
#pragma unroll
    for (int u = 0; u < 2; u++) {
      int q = qbase + u * 16 + r;
      unsigned short* po = Opb + ((size_t)sp * NROWS + q) * DIM;
#pragma unroll
      for (int dc = 0; dc < 8; dc++) {
        uint2 pk;
        pk.x = cvtpk_bf16(oacc[u][dc][0], oacc[u][dc][1]);
        pk.y = cvtpk_bf16(oacc[u][dc][2], oacc[u][dc][3]);
        *(uint2*)&po[dc * 16 + 4 * g] = pk;
      }
      if (g == 0) Lp[(size_t)sp * NROWS + q] = lsum[u];
    }
  }
}

// ------------------------- KV-split combine (bf16 partials, plain sum) -------------------------
__global__ __launch_bounds__(256) void combine(
    const unsigned short* __restrict__ Opb, const float* __restrict__ Lp,
    float* __restrict__ out, int S)
{
  int gid = blockIdx.x * 256 + threadIdx.x;    // q*32 + d4
  int q = gid >> 5, d4 = gid & 31;
  float den = 0.f, n0 = 0.f, n1 = 0.f, n2 = 0.f, n3 = 0.f;
  for (int s = 0; s < S; s++) {
    den += Lp[(size_t)s * NROWS + q];
    ushort4v h = *(const ushort4v*)&Opb[((size_t)s * NROWS + q) * DIM + d4 * 4];
    n0 += __builtin_bit_cast(float, (unsigned)h[0] << 16);
    n1 += __builtin_bit_cast(float, (unsigned)h[1] << 16);
    n2 += __builtin_bit_cast(float, (unsigned)h[2] << 16);
    n3 += __builtin_bit_cast(float, (unsigned)h[3] << 16);
  }
  float inv = 1.f / den;
  float4 o = {n0 * inv, n1 * inv, n2 * inv, n3 * inv};
  *(float4*)&out[(size_t)q * DIM + d4 * 4] = o;
}

// ------------------------- launcher -------------------------
extern "C" void kernel_launch(void* const* d_in, const int* in_sizes, int n_in,
                              void* d_out, int out_size, void* d_ws, size_t ws_size,
                              hipStream_t stream)
{
  (void)in_sizes; (void)n_in; (void)out_size;
  const float* x = (const float*)d_in[0];
  const float* W = (const float*)d_in[1];
  const float* b = (const float*)d_in[2];
  float* out = (float*)d_out;
  char* ws = (char*)d_ws;

  unsigned short* Q  = (unsigned short*)ws;
  unsigned short* K  = Q + (size_t)NROWS * DIM;
  unsigned short* Vt = K + (size_t)NROWS * DIM;
  const size_t qkvB = (size_t)3 * NROWS * DIM * 2;

  auto need = [&](int S) {
    return qkvB + (size_t)S * NROWS * DIM * 2 + (size_t)S * NROWS * 4;
  };
  int S; bool direct = false;
  if      (ws_size >= need(16)) S = 16;
  else if (ws_size >= need(8))  S = 8;
  else if (ws_size >= need(4))  S = 4;
  else if (ws_size >= need(1))  S = 1;
  else { S = 1; direct = true; }

  unsigned short* Opb = (unsigned short*)(ws + qkvB);
  float* Lp = (float*)(Opb + (size_t)S * NROWS * DIM);

  qkv_proj<<<dim3(128, 6), 256, 0, stream>>>(x, W, b, Q, K, Vt);
  attn<<<dim3(64, S), 256, 0, stream>>>(Q, K, Vt, Opb, Lp,
                                        direct ? out : nullptr, NROWS / S);
  if (!direct) combine<<<1024, 256, 0, stream>>>(Opb, Lp, out, S);
}

// Round 7
// 67.587 us; speedup vs baseline: 1.3491x; 1.3491x over previous
//
#include <hip/hip_runtime.h>
#include <hip/hip_bf16.h>

#define NROWS 8192
#define DIM 128

typedef short short8 __attribute__((ext_vector_type(8)));
typedef float f32x4 __attribute__((ext_vector_type(4)));
typedef unsigned short ushort4v __attribute__((ext_vector_type(4)));

__device__ __forceinline__ unsigned short bf16r(float f) {
  unsigned int u = __builtin_bit_cast(unsigned int, f);
  u += 0x7fffu + ((u >> 16) & 1u);   // round-to-nearest-even
  return (unsigned short)(u >> 16);
}
__device__ __forceinline__ short8 asbf8(uint4 v) { return __builtin_bit_cast(short8, v); }

__device__ __forceinline__ unsigned cvtpk_bf16(float lo, float hi) {
  unsigned r;
  asm("v_cvt_pk_bf16_f32 %0, %1, %2" : "=v"(r) : "v"(lo), "v"(hi));
  return r;
}
// v_permlane32_swap: rows2,3 of a <-> rows0,1 of b  => a=[a0,a1,b0,b1], b=[a2,a3,b2,b3]
__device__ __forceinline__ void pl32swap(unsigned& a, unsigned& b) {
  asm("v_permlane32_swap_b32 %0, %1" : "+v"(a), "+v"(b));
}
// v_permlane16_swap: rows1,3 of a <-> rows0,2 of b  => a=[a0,b0,a2,b2], b=[a1,b1,a3,b3]
__device__ __forceinline__ void pl16swap(unsigned& a, unsigned& b) {
  asm("v_permlane16_swap_b32 %0, %1" : "+v"(a), "+v"(b));
}

// async global->LDS, 16B per lane; LDS dest must be linear (base + lane*16)
__device__ __forceinline__ void gload_lds16(const void* g, void* l) {
  __builtin_amdgcn_global_load_lds(
      (const __attribute__((address_space(1))) void*)g,
      (__attribute__((address_space(3))) void*)l, 16, 0, 0);
}

// ------------------------- QKV projection (f32, LDS-staged) -------------------------
// Q is pre-scaled by log2(e) so attention can use exp2 directly.
__global__ __launch_bounds__(256) void qkv_proj(
    const float* __restrict__ x, const float* __restrict__ W, const float* __restrict__ bias,
    unsigned short* __restrict__ Q, unsigned short* __restrict__ K, unsigned short* __restrict__ Vt)
{
  __shared__ float sX[64 * 132];
  __shared__ float sW[64 * 132];
  __shared__ unsigned short sT[64 * 72];

  const int rt = blockIdx.x;                // 128 row tiles of 64
  const int ct = blockIdx.y;                // 6 col tiles of 64 (0,1->Q 2,3->K 4,5->V)
  const int t = threadIdx.x;

  const float4* xg = (const float4*)(x + (size_t)rt * 64 * DIM);
  const float4* wg = (const float4*)(W + (size_t)ct * 64 * DIM);
#pragma unroll
  for (int j = 0; j < 8; j++) {
    int i = t + 256 * j;
    int row = i >> 5, c4 = i & 31;
    *(float4*)&sX[row * 132 + c4 * 4] = xg[i];
    *(float4*)&sW[row * 132 + c4 * 4] = wg[i];
  }
  __syncthreads();

  const int tx = t & 15, ty = t >> 4;
  const int c0 = ct * 64 + tx * 4;

  float acc[4][4] = {};
#pragma unroll 8
  for (int k4 = 0; k4 < 32; k4++) {
    float4 xv[4], wv[4];
#pragma unroll
    for (int i = 0; i < 4; i++) xv[i] = *(const float4*)&sX[(ty * 4 + i) * 132 + k4 * 4];
#pragma unroll
    for (int j = 0; j < 4; j++) wv[j] = *(const float4*)&sW[(tx * 4 + j) * 132 + k4 * 4];
#pragma unroll
    for (int i = 0; i < 4; i++)
#pragma unroll
      for (int j = 0; j < 4; j++) {
        float s = acc[i][j];
        s = fmaf(xv[i].x, wv[j].x, s);
        s = fmaf(xv[i].y, wv[j].y, s);
        s = fmaf(xv[i].z, wv[j].z, s);
        s = fmaf(xv[i].w, wv[j].w, s);
        acc[i][j] = s;
      }
  }

  float bv[4];
#pragma unroll
  for (int j = 0; j < 4; j++) bv[j] = bias[c0 + j];

  if (ct < 4) {
    unsigned short* dst = (ct < 2) ? Q : K;
    const int cc = (ct < 2) ? c0 : c0 - 128;
    const float scale = (ct < 2) ? 1.44269504088896f : 1.0f;   // log2(e) folded into Q
#pragma unroll
    for (int i = 0; i < 4; i++) {
      int row = rt * 64 + ty * 4 + i;
      ushort4v h;
#pragma unroll
      for (int j = 0; j < 4; j++) h[j] = bf16r((acc[i][j] + bv[j]) * scale);
      *(ushort4v*)&dst[(size_t)row * DIM + cc] = h;
    }
  } else {
#pragma unroll
    for (int i = 0; i < 4; i++)
#pragma unroll
      for (int j = 0; j < 4; j++)
        sT[(tx * 4 + j) * 72 + ty * 4 + i] = bf16r(acc[i][j] + bv[j]);
    __syncthreads();
    const int dl = t & 63, chunk = t >> 6;
    const int dg = (ct - 4) * 64 + dl;
    uint4* dst = (uint4*)(Vt + (size_t)dg * NROWS + rt * 64 + chunk * 16);
    const uint4* src = (const uint4*)&sT[dl * 72 + chunk * 16];
    dst[0] = src[0];
    dst[1] = src[1];
  }
}

// ------------------------- flash attention (bf16 MFMA, swapped operands) -------------------------
// S^T = mfma(A=K, B=Q): lane (r,g) reg holds S[q=r][k=16kc+4g+reg].
// p = exp2(s) (Q pre-scaled); P^T packed to bf16 (cvt_pk) and moved to the PV
// B-fragment layout with v_permlane16/32_swap (pure VALU, no LDS traffic).
// O^T = mfma(A=V^T, B=P^T). K,V both double-buffered (64 KB LDS, 2 blocks/CU);
// single barrier per iteration: prefetch issued at top, drained at bottom.
__global__ __launch_bounds__(256, 2) void attn(
    const unsigned short* __restrict__ Q, const unsigned short* __restrict__ K,
    const unsigned short* __restrict__ Vt,
    unsigned short* __restrict__ Opb, float* __restrict__ Lp,
    float* __restrict__ outDirect, int kvlen)
{
  __shared__ uint4 sK[2][64 * 16];             // K tile [64][128] bf16, swizzled
  __shared__ uint4 sV[2][128 * 8];             // Vt tile [128][64] bf16, swizzled

  const int t = threadIdx.x;
  const int w = t >> 6, l = t & 63;
  const int r = l & 15, g = l >> 4;
  const int qt = blockIdx.x, sp = blockIdx.y;
  const int qbase = qt * 128 + w * 32;         // 32 q-rows per wave
  const int kb0 = sp * kvlen;
  const int rx = r & 7;

  // ---- staging geometry: slot p = j*256 + t (linear LDS dest) ----
  const unsigned short* kgp[4];
  const unsigned short* vgp[4];
#pragma unroll
  for (int j = 0; j < 4; j++) {
    int p = t + 256 * j;
    int krow = p >> 4, kc16 = (p & 15) ^ (krow & 7);
    kgp[j] = K + (size_t)(kb0 + krow) * DIM + kc16 * 8;
    int vrow = p >> 3, vd16 = (p & 7) ^ (vrow & 7);
    vgp[j] = Vt + (size_t)vrow * NROWS + kb0 + vd16 * 8;
  }

  uint4 qf[2][4];
#pragma unroll
  for (int u = 0; u < 2; u++) {
    const uint4* Qv = (const uint4*)(Q + (size_t)(qbase + u * 16 + r) * DIM);
#pragma unroll
    for (int f = 0; f < 4; f++) qf[u][f] = Qv[f * 4 + g];
  }

  float lsum[2] = {0.f, 0.f};
  f32x4 oacc[2][8];
#pragma unroll
  for (int u = 0; u < 2; u++)
#pragma unroll
    for (int dc = 0; dc < 8; dc++) oacc[u][dc] = (f32x4){0.f, 0.f, 0.f, 0.f};

  const int niter = kvlen >> 6;

  // prologue: stage tile 0 into buffer 0
#pragma unroll
  for (int j = 0; j < 4; j++) {
    gload_lds16(kgp[j], (uint4*)sK[0] + (t + 256 * j));
    gload_lds16(vgp[j], (uint4*)sV[0] + (t + 256 * j));
  }
  __syncthreads();

  int cur = 0;
  for (int it = 0; it < niter; ++it) {
    // ---- prefetch next tile into the other buffers (drained at bottom barrier) ----
    if (it + 1 < niter) {
      const size_t koff = (size_t)(it + 1) * 64 * DIM;
      const size_t voff = (size_t)(it + 1) * 64;
      const int nb = cur ^ 1;
#pragma unroll
      for (int j = 0; j < 4; j++) {
        gload_lds16(kgp[j] + koff, (uint4*)sK[nb] + (t + 256 * j));
        gload_lds16(vgp[j] + voff, (uint4*)sV[nb] + (t + 256 * j));
      }
    }

    // ---- S^T = K Q^T (swapped operands) ----
    f32x4 sacc[2][4];
#pragma unroll
    for (int u = 0; u < 2; u++)
#pragma unroll
      for (int kc = 0; kc < 4; kc++) sacc[u][kc] = (f32x4){0.f, 0.f, 0.f, 0.f};
#pragma unroll
    for (int kc = 0; kc < 4; kc++)
#pragma unroll
      for (int f = 0; f < 4; f++) {
        uint4 kf = sK[cur][(kc * 16 + r) * 16 + ((f * 4 + g) ^ rx)];
        sacc[0][kc] = __builtin_amdgcn_mfma_f32_16x16x32_bf16(asbf8(kf), asbf8(qf[0][f]), sacc[0][kc], 0, 0, 0);
        sacc[1][kc] = __builtin_amdgcn_mfma_f32_16x16x32_bf16(asbf8(kf), asbf8(qf[1][f]), sacc[1][kc], 0, 0, 0);
      }

    // ---- p = exp2(s); per-lane partial sums; pack pairs to bf16 ----
    unsigned c32[2][4][2];
#pragma unroll
    for (int u = 0; u < 2; u++)
#pragma unroll
      for (int kc = 0; kc < 4; kc++) {
        float p0 = __builtin_amdgcn_exp2f(sacc[u][kc][0]);
        float p1 = __builtin_amdgcn_exp2f(sacc[u][kc][1]);
        float p2 = __builtin_amdgcn_exp2f(sacc[u][kc][2]);
        float p3 = __builtin_amdgcn_exp2f(sacc[u][kc][3]);
        lsum[u] += (p0 + p1) + (p2 + p3);
        c32[u][kc][0] = cvtpk_bf16(p0, p1);
        c32[u][kc][1] = cvtpk_bf16(p2, p3);
      }

    // ---- redistribute P^T to B-fragment layout (pure VALU permlane swaps) ----
    // dst lane (r,g) dword d <- c32[2ka+(g>>1)][d&1] from lane group 2(g&1)+(d>>1)
    uint4 bfrag[2][2];
#pragma unroll
    for (int u = 0; u < 2; u++)
#pragma unroll
      for (int ka = 0; ka < 2; ka++) {
        unsigned x0 = c32[u][2 * ka][0],     x1 = c32[u][2 * ka][1];
        unsigned y0 = c32[u][2 * ka + 1][0], y1 = c32[u][2 * ka + 1][1];
        pl32swap(x0, y0);   // x0=[x0g0,x0g1,y0g0,y0g1]  y0=[x0g2,x0g3,y0g2,y0g3]
        pl16swap(x0, y0);   // x0=[x0g0,x0g2,y0g0,y0g2]=bf.x  y0=bf.z
        pl32swap(x1, y1);
        pl16swap(x1, y1);   // x1=bf.y  y1=bf.w
        bfrag[u][ka] = (uint4){x0, x1, y0, y1};
      }

    // ---- O^T += V^T P^T (vf shared across both q-subtiles) ----
#pragma unroll
    for (int dc = 0; dc < 8; dc++) {
      uint4 vf0 = sV[cur][(dc * 16 + r) * 8 + (g ^ rx)];
      uint4 vf1 = sV[cur][(dc * 16 + r) * 8 + ((4 + g) ^ rx)];
      oacc[0][dc] = __builtin_amdgcn_mfma_f32_16x16x32_bf16(asbf8(vf0), asbf8(bfrag[0][0]), oacc[0][dc], 0, 0, 0);
      oacc[0][dc] = __builtin_amdgcn_mfma_f32_16x16x32_bf16(asbf8(vf1), asbf8(bfrag[0][1]), oacc[0][dc], 0, 0, 0);
      oacc[1][dc] = __builtin_amdgcn_mfma_f32_16x16x32_bf16(asbf8(vf0), asbf8(bfrag[1][0]), oacc[1][dc], 0, 0, 0);
      oacc[1][dc] = __builtin_amdgcn_mfma_f32_16x16x32_bf16(asbf8(vf1), asbf8(bfrag[1][1]), oacc[1][dc], 0, 0, 0);
    }

    __syncthreads();                           // drain prefetch; free cur buffers
    cur ^= 1;
  }

  // ---- reduce row-sums across the 4 g-groups ----
#pragma unroll
  for (int u = 0; u < 2; u++) {
    float v = lsum[u];
    v += __shfl_xor(v, 16);
    v += __shfl_xor(v, 32);
    lsum[u] = v;
  }

  // ---- epilogue: lane (r,g) holds O^T[d=16dc+4g+reg][q=qbase+u*16+r] ----
  if (outDirect) {
#pragma unroll
    for (int u = 0; u < 2; u++) {
      float inv = 1.f / lsum[u];
      int q = qbase + u * 16 + r;
#pragma unroll
      for (int dc = 0; dc < 8; dc++) {
        f32x4 o = oacc[u][dc] * inv;
        *(f32x4*)&outDirect[(size_t)q * DIM + dc * 16 + 4 * g] = o;
      }
    }
  } else {
#pragma unroll
    for (int u = 0; u < 2; u++) {
      int q = qbase + u * 16 + r;
      unsigned short* po = Opb + ((size_t)sp * NROWS + q) * DIM;
#pragma unroll
      for (int dc = 0; dc < 8; dc++) {
        uint2 pk;
        pk.x = cvtpk_bf16(oacc[u][dc][0], oacc[u][dc][1]);
        pk.y = cvtpk_bf16(oacc[u][dc][2], oacc[u][dc][3]);
        *(uint2*)&po[dc * 16 + 4 * g] = pk;
      }
      if (g == 0) Lp[(size_t)sp * NROWS + q] = lsum[u];
    }
  }
}

// ------------------------- KV-split combine (bf16 partials, plain sum) -------------------------
__global__ __launch_bounds__(256) void combine(
    const unsigned short* __restrict__ Opb, const float* __restrict__ Lp,
    float* __restrict__ out, int S)
{
  int gid = blockIdx.x * 256 + threadIdx.x;    // q*32 + d4
  int q = gid >> 5, d4 = gid & 31;
  float den = 0.f, n0 = 0.f, n1 = 0.f, n2 = 0.f, n3 = 0.f;
  for (int s = 0; s < S; s++) {
    den += Lp[(size_t)s * NROWS + q];
    ushort4v h = *(const ushort4v*)&Opb[((size_t)s * NROWS + q) * DIM + d4 * 4];
    n0 += __builtin_bit_cast(float, (unsigned)h[0] << 16);
    n1 += __builtin_bit_cast(float, (unsigned)h[1] << 16);
    n2 += __builtin_bit_cast(float, (unsigned)h[2] << 16);
    n3 += __builtin_bit_cast(float, (unsigned)h[3] << 16);
  }
  float inv = 1.f / den;
  float4 o = {n0 * inv, n1 * inv, n2 * inv, n3 * inv};
  *(float4*)&out[(size_t)q * DIM + d4 * 4] = o;
}

// ------------------------- launcher -------------------------
extern "C" void kernel_launch(void* const* d_in, const int* in_sizes, int n_in,
                              void* d_out, int out_size, void* d_ws, size_t ws_size,
                              hipStream_t stream)
{
  (void)in_sizes; (void)n_in; (void)out_size;
  const float* x = (const float*)d_in[0];
  const float* W = (const float*)d_in[1];
  const float* b = (const float*)d_in[2];
  float* out = (float*)d_out;
  char* ws = (char*)d_ws;

  unsigned short* Q  = (unsigned short*)ws;
  unsigned short* K  = Q + (size_t)NROWS * DIM;
  unsigned short* Vt = K + (size_t)NROWS * DIM;
  const size_t qkvB = (size_t)3 * NROWS * DIM * 2;

  auto need = [&](int S) {
    return qkvB + (size_t)S * NROWS * DIM * 2 + (size_t)S * NROWS * 4;
  };
  int S; bool direct = false;
  if      (ws_size >= need(8))  S = 8;
  else if (ws_size >= need(4))  S = 4;
  else if (ws_size >= need(2))  S = 2;
  else if (ws_size >= need(1))  S = 1;
  else { S = 1; direct = true; }

  unsigned short* Opb = (unsigned short*)(ws + qkvB);
  float* Lp = (float*)(Opb + (size_t)S * NROWS * DIM);

  qkv_proj<<<dim3(128, 6), 256, 0, stream>>>(x, W, b, Q, K, Vt);
  attn<<<dim3(64, S), 256, 0, stream>>>(Q, K, Vt, Opb, Lp,
                                        direct ? out : nullptr, NROWS / S);
  if (!direct) combine<<<1024, 256, 0, stream>>>(Opb, Lp, out, S);
}